// Round 7
// baseline (644.432 us; speedup 1.0000x reference)
//
#include <hip/hip_runtime.h>
#include <hip/hip_bf16.h>

typedef unsigned short u16;
typedef unsigned int u32;
typedef __attribute__((ext_vector_type(4))) unsigned int u32x4;
typedef __attribute__((ext_vector_type(4))) float f32x4;
typedef __attribute__((ext_vector_type(8))) short bf16x8;    // 8 bf16 (4 VGPRs)
typedef __attribute__((ext_vector_type(16))) float f32x16;   // 32x32 MFMA C/D

__device__ __forceinline__ u32 cvtpk(float lo, float hi) {   // v_cvt_pk_bf16_f32
    __hip_bfloat162 h = __float22bfloat162_rn(make_float2(lo, hi));
    u32 r; __builtin_memcpy(&r, &h, 4);
    return r;
}
__device__ __forceinline__ int crow(int r, int hl) { return (r & 3) + 8 * (r >> 2) + 4 * hl; }

#define NROW 4096
#define CK 64
#define CV 128
#define VT_OFF 8192   // u16 idx: V^T [128 v][128 j] bf16 (32KB); K [128 j][64 c] at 0 (16KB)
#define SWK(R, o) ((((R) << 7) + (o)) ^ (((R) & 7) << 4))    // 128B-stride XOR swizzle
#define SWV(R, o) ((((R) << 8) + (o)) ^ (((R) & 15) << 4))   // 256B-stride XOR swizzle

// 512 blocks x 512 thr (8 waves). batch bb = bid&7 (XCD L2 affinity).
// Block owns q-tile pair {T_L = mIdx, T_H = 127-mIdx}: total slices
// (T_L+1)+(T_H+1) = 129 for EVERY block -> equal duration, no schedule tail.
// Waves: ts = w>>2 (0=heavy,1=light tile), h = w&3 (j-quarter).
// Staged KV tiles are 128 rows = 4 slices; wave handles slice jS = 4*tt+h.
__global__ __launch_bounds__(512, 4) void attn_k(const float* __restrict__ Qg,
                                                 const float* __restrict__ Kg,
                                                 const float* __restrict__ Vg,
                                                 float* __restrict__ O) {
    __shared__ __align__(16) u16 smem[24576];   // 48KB; combine overlays 33KB

    int bid = blockIdx.x;
    int bb   = bid & 7;
    int mIdx = bid >> 3;                 // 0..63
    int t    = threadIdx.x;
    int w    = t >> 6;
    int lane = t & 63;
    int ql = lane & 31, hl = lane >> 5;
    int ts = w >> 2;                     // 0 = heavy tile, 1 = light tile
    int h  = w & 3;                      // j-quarter
    int T_H = 127 - mIdx;
    int T  = ts ? mIdx : T_H;
    int qbw = T << 5;
    int NTb = (T_H >> 2) + 1;            // staged 128-row KV tiles

    const float* Qp = Qg + (size_t)bb * NROW * CK;
    const float* Kp = Kg + (size_t)bb * NROW * CK;
    const float* Vp = Vg + (size_t)bb * NROW * CV;

    const float qscale = 0.125f * 1.44269504088896f;   // 1/sqrt(64) * log2(e)

    // Q B-fragments (col=q=ql, k = kc*16 + hl*8 + e), scale folded
    bf16x8 qf[4];
#pragma unroll
    for (int kc = 0; kc < 4; kc++) {
        const float* qp = Qp + (size_t)(qbw + ql) * CK + kc * 16 + hl * 8;
        f32x4 a = *(const f32x4*)qp;
        f32x4 b = *(const f32x4*)(qp + 4);
        u32x4 qq;
        qq[0] = cvtpk(a[0] * qscale, a[1] * qscale);
        qq[1] = cvtpk(a[2] * qscale, a[3] * qscale);
        qq[2] = cvtpk(b[0] * qscale, b[1] * qscale);
        qq[3] = cvtpk(b[2] * qscale, b[3] * qscale);
        qf[kc] = __builtin_bit_cast(bf16x8, qq);
    }

    f32x16 acc[4];
#pragma unroll
    for (int vs = 0; vs < 4; vs++)
#pragma unroll
        for (int r = 0; r < 16; r++) acc[vs][r] = 0.f;
    float l = 0.f;

    // staging (512 thr): K row jK = t>>2, 16 floats at col oc*16 -> 2 u16x8 LDS
    //                    V rows jq8*8..+7, v-cols vg*4..+3 -> 4 transposed u16x8
    int jK = t >> 2, oc = t & 3;
    int jq8 = t & 15, vg = t >> 4;       // vg 0..31
    const float* kSrc = Kp + (size_t)jK * CK + oc * 16;
    const float* vSrc = Vp + (size_t)(jq8 * 8) * CV + vg * 4;

    f32x4 ka0, ka1, ka2, ka3;
    f32x4 va0, va1, va2, va3, va4, va5, va6, va7;
    ka0 = *(const f32x4*)(kSrc);     ka1 = *(const f32x4*)(kSrc + 4);
    ka2 = *(const f32x4*)(kSrc + 8); ka3 = *(const f32x4*)(kSrc + 12);
    va0 = *(const f32x4*)(vSrc);          va1 = *(const f32x4*)(vSrc + CV);
    va2 = *(const f32x4*)(vSrc + 2 * CV); va3 = *(const f32x4*)(vSrc + 3 * CV);
    va4 = *(const f32x4*)(vSrc + 4 * CV); va5 = *(const f32x4*)(vSrc + 5 * CV);
    va6 = *(const f32x4*)(vSrc + 6 * CV); va7 = *(const f32x4*)(vSrc + 7 * CV);

    for (int tt = 0; tt < NTb; ++tt) {
        __syncthreads();   // WAR: prior tile's LDS reads complete
        {   // ---- store prefetched tile (fp32 regs -> bf16 LDS, swizzled) ----
            u32x4 kk0, kk1;
            kk0[0] = cvtpk(ka0[0], ka0[1]); kk0[1] = cvtpk(ka0[2], ka0[3]);
            kk0[2] = cvtpk(ka1[0], ka1[1]); kk0[3] = cvtpk(ka1[2], ka1[3]);
            kk1[0] = cvtpk(ka2[0], ka2[1]); kk1[1] = cvtpk(ka2[2], ka2[3]);
            kk1[2] = cvtpk(ka3[0], ka3[1]); kk1[3] = cvtpk(ka3[2], ka3[3]);
            *(u32x4*)&smem[SWK(jK, oc * 32) >> 1]      = kk0;
            *(u32x4*)&smem[SWK(jK, oc * 32 + 16) >> 1] = kk1;
#pragma unroll
            for (int i = 0; i < 4; i++) {
                int v = vg * 4 + i;
                u32x4 vv;
                vv[0] = cvtpk(va0[i], va1[i]); vv[1] = cvtpk(va2[i], va3[i]);
                vv[2] = cvtpk(va4[i], va5[i]); vv[3] = cvtpk(va6[i], va7[i]);
                *(u32x4*)&smem[VT_OFF + (SWV(v, jq8 * 16) >> 1)] = vv;
            }
        }
        __syncthreads();   // RAW: tile staged
        {   // ---- prefetch next tile into regs (consumed next round) ----
            int nt = (tt + 1 < NTb) ? (tt + 1) : tt;
            const float* kp = kSrc + (size_t)nt * (128 * CK);
            const float* vp = vSrc + (size_t)nt * (128 * CV);
            ka0 = *(const f32x4*)(kp);     ka1 = *(const f32x4*)(kp + 4);
            ka2 = *(const f32x4*)(kp + 8); ka3 = *(const f32x4*)(kp + 12);
            va0 = *(const f32x4*)(vp);          va1 = *(const f32x4*)(vp + CV);
            va2 = *(const f32x4*)(vp + 2 * CV); va3 = *(const f32x4*)(vp + 3 * CV);
            va4 = *(const f32x4*)(vp + 4 * CV); va5 = *(const f32x4*)(vp + 5 * CV);
            va6 = *(const f32x4*)(vp + 6 * CV); va7 = *(const f32x4*)(vp + 7 * CV);
        }

        int jS = 4 * tt + h;               // this wave's 32-j slice
        if (jS > T) continue;              // above diagonal (barriers already done)
        int sl = jS & 3;                   // slice within staged tile

        // ---- QK^T swapped (S = K x Q): 2 independent 2-chains ----
        bf16x8 kf0 = *(const bf16x8*)&smem[SWK(sl * 32 + ql, 0 * 32 + hl * 16) >> 1];
        bf16x8 kf1 = *(const bf16x8*)&smem[SWK(sl * 32 + ql, 1 * 32 + hl * 16) >> 1];
        bf16x8 kf2 = *(const bf16x8*)&smem[SWK(sl * 32 + ql, 2 * 32 + hl * 16) >> 1];
        bf16x8 kf3 = *(const bf16x8*)&smem[SWK(sl * 32 + ql, 3 * 32 + hl * 16) >> 1];
        f32x16 Sa, Sb;
#pragma unroll
        for (int r = 0; r < 16; r++) { Sa[r] = 0.f; Sb[r] = 0.f; }
        __builtin_amdgcn_s_setprio(1);
        Sa = __builtin_amdgcn_mfma_f32_32x32x16_bf16(kf0, qf[0], Sa, 0, 0, 0);
        Sb = __builtin_amdgcn_mfma_f32_32x32x16_bf16(kf2, qf[2], Sb, 0, 0, 0);
        Sa = __builtin_amdgcn_mfma_f32_32x32x16_bf16(kf1, qf[1], Sa, 0, 0, 0);
        Sb = __builtin_amdgcn_mfma_f32_32x32x16_bf16(kf3, qf[3], Sb, 0, 0, 0);
        __builtin_amdgcn_s_setprio(0);

        // ---- P = exp2(S), strict-causal mask on the diagonal slice ----
        float P[16];
        bool diag = (jS == T);
#pragma unroll
        for (int r = 0; r < 16; r++) {
            float pr = __builtin_exp2f(Sa[r] + Sb[r]);
            if (diag) pr = (crow(r, hl) >= ql) ? 0.f : pr;
            P[r] = pr;
        }
        {
            float s0 = (P[0] + P[1]) + (P[2] + P[3]);
            float s1 = (P[4] + P[5]) + (P[6] + P[7]);
            float s2 = (P[8] + P[9]) + (P[10] + P[11]);
            float s3 = (P[12] + P[13]) + (P[14] + P[15]);
            l += (s0 + s1) + (s2 + s3);
        }

        // ---- P -> PV A-fragments: 8 cvt_pk + 4 batched shfl + 8 selects ----
        u32 A0 = cvtpk(P[0], P[1]),   B0 = cvtpk(P[2], P[3]);
        u32 A1 = cvtpk(P[4], P[5]),   B1 = cvtpk(P[6], P[7]);
        u32 A2 = cvtpk(P[8], P[9]),   B2 = cvtpk(P[10], P[11]);
        u32 A3 = cvtpk(P[12], P[13]), B3 = cvtpk(P[14], P[15]);
        u32 s1 = hl ? A0 : A1, s2 = hl ? B0 : B1;
        u32 s3 = hl ? A2 : A3, s4 = hl ? B2 : B3;
        u32 r1 = (u32)__shfl_xor((int)s1, 32);
        u32 r2 = (u32)__shfl_xor((int)s2, 32);
        u32 r3 = (u32)__shfl_xor((int)s3, 32);
        u32 r4 = (u32)__shfl_xor((int)s4, 32);

        // ---- V fragments (issued while shfls are in flight) ----
        bf16x8 vf0[4], vf1[4];
#pragma unroll
        for (int vs = 0; vs < 4; vs++) {
            vf0[vs] = *(const bf16x8*)&smem[VT_OFF + (SWV(vs * 32 + ql, sl * 64 + hl * 16) >> 1)];
            vf1[vs] = *(const bf16x8*)&smem[VT_OFF + (SWV(vs * 32 + ql, sl * 64 + 32 + hl * 16) >> 1)];
        }

        u32x4 w0, w1;
        w0[0] = hl ? r1 : A0; w0[1] = hl ? r2 : B0;
        w0[2] = hl ? A1 : r1; w0[3] = hl ? B1 : r2;
        w1[0] = hl ? r3 : A2; w1[1] = hl ? r4 : B2;
        w1[2] = hl ? A3 : r3; w1[3] = hl ? B3 : r4;
        bf16x8 pa0 = __builtin_bit_cast(bf16x8, w0);
        bf16x8 pa1 = __builtin_bit_cast(bf16x8, w1);

        // ---- PV: 4 independent chains of 2 ----
        __builtin_amdgcn_s_setprio(1);
#pragma unroll
        for (int vs = 0; vs < 4; vs++)
            acc[vs] = __builtin_amdgcn_mfma_f32_32x32x16_bf16(pa0, vf0[vs], acc[vs], 0, 0, 0);
#pragma unroll
        for (int vs = 0; vs < 4; vs++)
            acc[vs] = __builtin_amdgcn_mfma_f32_32x32x16_bf16(pa1, vf1[vs], acc[vs], 0, 0, 0);
        __builtin_amdgcn_s_setprio(0);
    }

    // ---- 4-way j-split combine (plain adds: no softmax shift used) ----
    __syncthreads();                            // all tile reads done; overlay LDS
    float* cmf = (float*)smem;                  // [2][32 q][128 v] f32 = 32KB
    float* lAf = cmf + 8192;                    // [2][32] f32
    float lw = l + __shfl_xor(l, 32);           // wave-local l for q=ql
    int cbase = ts * 4096;

    if (h == 0) {
#pragma unroll
        for (int vs = 0; vs < 4; vs++)
#pragma unroll
            for (int r = 0; r < 16; r++)
                cmf[cbase + crow(r, hl) * 128 + vs * 32 + ql] = acc[vs][r];
        if (lane < 32) lAf[ts * 32 + lane] = lw;
    }
    __syncthreads();
    if (h == 1) {
#pragma unroll
        for (int vs = 0; vs < 4; vs++)
#pragma unroll
            for (int r = 0; r < 16; r++)
                cmf[cbase + crow(r, hl) * 128 + vs * 32 + ql] += acc[vs][r];
        if (lane < 32) lAf[ts * 32 + lane] += lw;
    }
    __syncthreads();
    if (h == 2) {
#pragma unroll
        for (int vs = 0; vs < 4; vs++)
#pragma unroll
            for (int r = 0; r < 16; r++)
                cmf[cbase + crow(r, hl) * 128 + vs * 32 + ql] += acc[vs][r];
        if (lane < 32) lAf[ts * 32 + lane] += lw;
    }
    __syncthreads();
    if (h == 3) {
        float ltot = lAf[ts * 32 + ql] + lw;
        float inv = (qbw + ql == 0) ? 0.f : 1.f / ltot;   // global row 0 -> 0
        float inv_r[16];
#pragma unroll
        for (int r = 0; r < 16; r++) inv_r[r] = __shfl(inv, crow(r, hl));
        float* Og = O + ((size_t)bb * NROW + qbw) * CV;
#pragma unroll
        for (int vs = 0; vs < 4; vs++)
#pragma unroll
            for (int r = 0; r < 16; r++) {
                int q = crow(r, hl);
                float val = (cmf[cbase + q * 128 + vs * 32 + ql] + acc[vs][r]) * inv_r[r];
                Og[(size_t)q * CV + vs * 32 + ql] = val;
            }
    }
}

// ---------------------------------------------------------------------------
extern "C" void kernel_launch(void* const* d_in, const int* in_sizes, int n_in,
                              void* d_out, int out_size, void* d_ws, size_t ws_size,
                              hipStream_t stream) {
    const float* Q = (const float*)d_in[0];
    const float* K = (const float*)d_in[1];
    const float* V = (const float*)d_in[2];
    float* out = (float*)d_out;
    hipLaunchKernelGGL(attn_k, dim3(512), dim3(512), 0, stream, Q, K, V, out);
}

// Round 8
// 84.025 us; speedup vs baseline: 7.6695x; 7.6695x over previous
//
#include <hip/hip_runtime.h>
#include <hip/hip_bf16.h>

typedef unsigned short u16;
typedef unsigned int u32;
typedef __attribute__((ext_vector_type(2))) unsigned int u32x2;
typedef __attribute__((ext_vector_type(4))) unsigned int u32x4;
typedef __attribute__((ext_vector_type(4))) float f32x4;
typedef __attribute__((ext_vector_type(8))) short bf16x8;    // 8 bf16 (4 VGPRs)
typedef __attribute__((ext_vector_type(16))) float f32x16;   // 32x32 MFMA C/D

__device__ __forceinline__ u32 cvtpk(float lo, float hi) {   // v_cvt_pk_bf16_f32
    __hip_bfloat162 h = __float22bfloat162_rn(make_float2(lo, hi));
    u32 r; __builtin_memcpy(&r, &h, 4);
    return r;
}
__device__ __forceinline__ int crow(int r, int hl) { return (r & 3) + 8 * (r >> 2) + 4 * hl; }

#define NROW 4096
#define CK 64
#define CV 128
#define BUF 24576     // u16 per LDS buffer (48KB): K img 16KB + V^T img 32KB
#define VT_OFF 8192   // u16 offset of V^T within buffer
// K tile [128 j][64 c] bf16, 128B rows:
#define SWK(R, o) ((((R) << 7) + (o)) ^ (((R) & 7) << 4))
// V^T tile [128 v][128 j] bf16, 256B rows; g(v) spreads BOTH the 8B transposed
// writes (lanes vary v>>3) and the b128 reads (lanes vary v&31, ~2-way = free):
#define SWVG(R) ((((R) >> 3) & 15) ^ (((R) & 7) << 1))
#define SWV(R, o) ((((R) << 8) + (o)) ^ (SWVG(R) << 4))

// 256 blocks x 512 thr (8 waves), 1 block/CU (96KB LDS).
// Block: batch bb=bid&7 (XCD L2 affinity), pair index u=bid>>3 (0..31).
// Processes 64-row q-unit uL=u (q-tiles 2u,2u+1), then uH=63-u, sequentially.
// Waves: qsub=w>>2 selects the 32-row q-tile (2*unit+qsub), jq=w&3 the
// j-quarter (32-row slice) of each 128-row staged KV tile.
// rounds = (2uL+1)/4+1 + (2uH+1)/4+1 == 33 for EVERY block (equal duration).
// Pipeline: per round {store prefetched tile -> 1 barrier -> compute + prefetch
// next}; barrier of round rr-1 separates buf[rr&1] reuse (WAR safe).
__global__ __launch_bounds__(512, 2) void attn_k(const float* __restrict__ Qg,
                                                 const float* __restrict__ Kg,
                                                 const float* __restrict__ Vg,
                                                 float* __restrict__ O) {
    __shared__ __align__(16) u16 smem[2 * BUF];   // 96KB

    int bid = blockIdx.x;
    int bb = bid & 7;
    int u  = bid >> 3;                 // 0..31
    int t  = threadIdx.x;
    int w  = t >> 6;
    int lane = t & 63;
    int ql = lane & 31, hl = lane >> 5;
    int qsub = w >> 2;                 // 0/1: q-tile within unit
    int jq   = w & 3;                  // j-quarter
    int uL = u, uH = 63 - u;
    int rA = ((2 * uL + 1) >> 2) + 1;  // light-phase rounds (rA+rB == 33)

    const float* Qp = Qg + (size_t)bb * NROW * CK;
    const float* Kp = Kg + (size_t)bb * NROW * CK;
    const float* Vp = Vg + (size_t)bb * NROW * CV;
    const float qscale = 0.125f * 1.44269504088896f;   // 1/sqrt(64)*log2(e)

    // ---- Q fragments (B-operand: col=q=ql, k=kc*16+hl*8+e), scale folded ----
    bf16x8 qf[4];
    auto loadQ = [&](int T) {
        const float* qb = Qp + (size_t)((T << 5) + ql) * CK;
#pragma unroll
        for (int kc = 0; kc < 4; kc++) {
            const float* qp = qb + kc * 16 + hl * 8;
            f32x4 a = *(const f32x4*)qp;
            f32x4 b2 = *(const f32x4*)(qp + 4);
            u32x4 qq;
            qq[0] = cvtpk(a[0] * qscale, a[1] * qscale);
            qq[1] = cvtpk(a[2] * qscale, a[3] * qscale);
            qq[2] = cvtpk(b2[0] * qscale, b2[1] * qscale);
            qq[3] = cvtpk(b2[2] * qscale, b2[3] * qscale);
            qf[kc] = __builtin_bit_cast(bf16x8, qq);
        }
    };
    int T_cur = 2 * uL + qsub;
    loadQ(T_cur);

    f32x16 acc[4];
#pragma unroll
    for (int vs = 0; vs < 4; vs++)
#pragma unroll
        for (int r = 0; r < 16; r++) acc[vs][r] = 0.f;
    float l = 0.f;

    // ---- staging maps (512 thr, 128-row tiles) ----
    // K: row jK=t>>2, col-quarter kc4=t&3 (16 floats -> 2 x 16B LDS)
    // V: v-cols vg*8..+7 (vg=t&15), j-rows jgrp*4..+3 (jgrp=t>>4) -> 8 x 8B LDS^T
    int jK = t >> 2, kc4 = t & 3;
    int vg = t & 15, jgrp = t >> 4;
    const float* kSrc = Kp + (size_t)jK * CK + kc4 * 16;
    const float* vSrc = Vp + (size_t)(jgrp * 4) * CV + vg * 8;

    f32x4 kr0, kr1, kr2, kr3;
    f32x4 va0, va1, va2, va3, vb0, vb1, vb2, vb3;
    auto prefetch = [&](int jb) {
        const float* kp = kSrc + (size_t)jb * CK;
        kr0 = *(const f32x4*)kp;       kr1 = *(const f32x4*)(kp + 4);
        kr2 = *(const f32x4*)(kp + 8); kr3 = *(const f32x4*)(kp + 12);
        const float* vp = vSrc + (size_t)jb * CV;
        va0 = *(const f32x4*)vp;            vb0 = *(const f32x4*)(vp + 4);
        va1 = *(const f32x4*)(vp + CV);     vb1 = *(const f32x4*)(vp + CV + 4);
        va2 = *(const f32x4*)(vp + 2 * CV); vb2 = *(const f32x4*)(vp + 2 * CV + 4);
        va3 = *(const f32x4*)(vp + 3 * CV); vb3 = *(const f32x4*)(vp + 3 * CV + 4);
    };
    auto store_tile = [&](int bufo) {
        u32x4 kk0, kk1;
        kk0[0] = cvtpk(kr0[0], kr0[1]); kk0[1] = cvtpk(kr0[2], kr0[3]);
        kk0[2] = cvtpk(kr1[0], kr1[1]); kk0[3] = cvtpk(kr1[2], kr1[3]);
        kk1[0] = cvtpk(kr2[0], kr2[1]); kk1[1] = cvtpk(kr2[2], kr2[3]);
        kk1[2] = cvtpk(kr3[0], kr3[1]); kk1[3] = cvtpk(kr3[2], kr3[3]);
        *(u32x4*)&smem[bufo + (SWK(jK, kc4 * 32) >> 1)]      = kk0;
        *(u32x4*)&smem[bufo + (SWK(jK, kc4 * 32 + 16) >> 1)] = kk1;
#pragma unroll
        for (int x = 0; x < 4; x++) {
            int v = vg * 8 + x;
            u32x2 vv; vv[0] = cvtpk(va0[x], va1[x]); vv[1] = cvtpk(va2[x], va3[x]);
            *(u32x2*)&smem[bufo + VT_OFF + (SWV(v, jgrp * 8) >> 1)] = vv;
        }
#pragma unroll
        for (int x = 0; x < 4; x++) {
            int v = vg * 8 + 4 + x;
            u32x2 vv; vv[0] = cvtpk(vb0[x], vb1[x]); vv[1] = cvtpk(vb2[x], vb3[x]);
            *(u32x2*)&smem[bufo + VT_OFF + (SWV(v, jgrp * 8) >> 1)] = vv;
        }
    };

    // ---- per-phase 4-way j-combine + output (scratch overlays a consumed buffer)
    auto combine = [&](int scratch, int Tq) {
        float* cm = (float*)(smem + scratch);   // [2 qsub][32 q][128 v] f32 (32KB)
        float* lA = cm + 8192;                  // [2][32]
        float lw = l + __shfl_xor(l, 32);
        if (jq == 0) {
#pragma unroll
            for (int vs = 0; vs < 4; vs++)
#pragma unroll
                for (int r = 0; r < 16; r++)
                    cm[qsub * 4096 + crow(r, hl) * 128 + vs * 32 + ql] = acc[vs][r];
            if (lane < 32) lA[qsub * 32 + lane] = lw;
        }
        __syncthreads();
        if (jq == 1) {
#pragma unroll
            for (int vs = 0; vs < 4; vs++)
#pragma unroll
                for (int r = 0; r < 16; r++)
                    cm[qsub * 4096 + crow(r, hl) * 128 + vs * 32 + ql] += acc[vs][r];
            if (lane < 32) lA[qsub * 32 + lane] += lw;
        }
        __syncthreads();
        if (jq == 2) {
#pragma unroll
            for (int vs = 0; vs < 4; vs++)
#pragma unroll
                for (int r = 0; r < 16; r++)
                    cm[qsub * 4096 + crow(r, hl) * 128 + vs * 32 + ql] += acc[vs][r];
            if (lane < 32) lA[qsub * 32 + lane] += lw;
        }
        __syncthreads();
        if (jq == 3) {
            float ltot = lA[qsub * 32 + ql] + lw;
            float inv = ((Tq << 5) + ql == 0) ? 0.f : 1.f / ltot;  // batch row 0 -> 0
            float inv_r[16];
#pragma unroll
            for (int r = 0; r < 16; r++) inv_r[r] = __shfl(inv, crow(r, hl));
            float* Og = O + ((size_t)bb * NROW + ((size_t)Tq << 5)) * CV;
#pragma unroll
            for (int vs = 0; vs < 4; vs++)
#pragma unroll
                for (int r = 0; r < 16; r++)
                    Og[(size_t)crow(r, hl) * CV + vs * 32 + ql] =
                        (cm[qsub * 4096 + crow(r, hl) * 128 + vs * 32 + ql] + acc[vs][r]) * inv_r[r];
        }
        __syncthreads();   // scratch free before it is re-staged
    };

    prefetch(0);   // tile 0 of light phase

    for (int rr = 0; rr < 33; ++rr) {
        int bufo = (rr & 1) * BUF;
        store_tile(bufo);
        __syncthreads();                    // the one barrier per round

        if (rr == rA) {                     // light phase done -> combine + reset
            combine(((rA - 1) & 1) * BUF, T_cur);
#pragma unroll
            for (int vs = 0; vs < 4; vs++)
#pragma unroll
                for (int r = 0; r < 16; r++) acc[vs][r] = 0.f;
            l = 0.f;
            T_cur = 2 * uH + qsub;
            loadQ(T_cur);
        }

        int tt = (rr < rA) ? rr : rr - rA;
        int jS = 4 * tt + jq;

        {   // prefetch next round's tile (all threads, before any divergence)
            int nr = rr + 1;
            int jb = (nr < rA) ? (nr << 7)
                               : ((nr <= 32 ? (nr - rA) : (32 - rA)) << 7);
            prefetch(jb);
        }

        if (jS > T_cur) continue;           // above diagonal; no barriers skipped

        // ---- QK^T swapped (S = K x Q), single 4-chain ----
        bf16x8 kf0 = *(const bf16x8*)&smem[bufo + (SWK(jq * 32 + ql, 0 * 32 + hl * 16) >> 1)];
        bf16x8 kf1 = *(const bf16x8*)&smem[bufo + (SWK(jq * 32 + ql, 1 * 32 + hl * 16) >> 1)];
        bf16x8 kf2 = *(const bf16x8*)&smem[bufo + (SWK(jq * 32 + ql, 2 * 32 + hl * 16) >> 1)];
        bf16x8 kf3 = *(const bf16x8*)&smem[bufo + (SWK(jq * 32 + ql, 3 * 32 + hl * 16) >> 1)];
        f32x16 S;
#pragma unroll
        for (int r = 0; r < 16; r++) S[r] = 0.f;
        __builtin_amdgcn_s_setprio(1);
        S = __builtin_amdgcn_mfma_f32_32x32x16_bf16(kf0, qf[0], S, 0, 0, 0);
        S = __builtin_amdgcn_mfma_f32_32x32x16_bf16(kf1, qf[1], S, 0, 0, 0);
        S = __builtin_amdgcn_mfma_f32_32x32x16_bf16(kf2, qf[2], S, 0, 0, 0);
        S = __builtin_amdgcn_mfma_f32_32x32x16_bf16(kf3, qf[3], S, 0, 0, 0);
        __builtin_amdgcn_s_setprio(0);

        // ---- P = exp2(S), strict-causal mask on the diagonal slice ----
        float P[16];
        bool diag = (jS == T_cur);
#pragma unroll
        for (int r = 0; r < 16; r++) {
            float pr = __builtin_exp2f(S[r]);
            if (diag) pr = (crow(r, hl) >= ql) ? 0.f : pr;
            P[r] = pr;
        }
        {
            float s0 = (P[0] + P[1]) + (P[2] + P[3]);
            float s1 = (P[4] + P[5]) + (P[6] + P[7]);
            float s2 = (P[8] + P[9]) + (P[10] + P[11]);
            float s3 = (P[12] + P[13]) + (P[14] + P[15]);
            l += (s0 + s1) + (s2 + s3);
        }

        // ---- P -> PV A-fragments: 8 cvt_pk + 4 batched shfl + selects ----
        u32 A0 = cvtpk(P[0], P[1]),   B0 = cvtpk(P[2], P[3]);
        u32 A1 = cvtpk(P[4], P[5]),   B1 = cvtpk(P[6], P[7]);
        u32 A2 = cvtpk(P[8], P[9]),   B2 = cvtpk(P[10], P[11]);
        u32 A3 = cvtpk(P[12], P[13]), B3 = cvtpk(P[14], P[15]);
        u32 s1 = hl ? A0 : A1, s2 = hl ? B0 : B1;
        u32 s3 = hl ? A2 : A3, s4 = hl ? B2 : B3;
        u32 r1 = (u32)__shfl_xor((int)s1, 32);
        u32 r2 = (u32)__shfl_xor((int)s2, 32);
        u32 r3 = (u32)__shfl_xor((int)s3, 32);
        u32 r4 = (u32)__shfl_xor((int)s4, 32);

        bf16x8 vf0[4], vf1[4];            // issued while shfls are in flight
#pragma unroll
        for (int vs = 0; vs < 4; vs++) {
            vf0[vs] = *(const bf16x8*)&smem[bufo + VT_OFF + (SWV(vs * 32 + ql, jq * 64 + hl * 16) >> 1)];
            vf1[vs] = *(const bf16x8*)&smem[bufo + VT_OFF + (SWV(vs * 32 + ql, jq * 64 + 32 + hl * 16) >> 1)];
        }

        u32x4 w0, w1;
        w0[0] = hl ? r1 : A0; w0[1] = hl ? r2 : B0;
        w0[2] = hl ? A1 : r1; w0[3] = hl ? B1 : r2;
        w1[0] = hl ? r3 : A2; w1[1] = hl ? r4 : B2;
        w1[2] = hl ? A3 : r3; w1[3] = hl ? B3 : r4;
        bf16x8 pa0 = __builtin_bit_cast(bf16x8, w0);
        bf16x8 pa1 = __builtin_bit_cast(bf16x8, w1);

        // ---- PV: 4 independent chains of 2 ----
        __builtin_amdgcn_s_setprio(1);
#pragma unroll
        for (int vs = 0; vs < 4; vs++)
            acc[vs] = __builtin_amdgcn_mfma_f32_32x32x16_bf16(pa0, vf0[vs], acc[vs], 0, 0, 0);
#pragma unroll
        for (int vs = 0; vs < 4; vs++)
            acc[vs] = __builtin_amdgcn_mfma_f32_32x32x16_bf16(pa1, vf1[vs], acc[vs], 0, 0, 0);
        __builtin_amdgcn_s_setprio(0);
    }

    __syncthreads();           // round-32 reads done before overlaying buf0
    combine(0, T_cur);         // heavy-phase combine + store
}

// ---------------------------------------------------------------------------
extern "C" void kernel_launch(void* const* d_in, const int* in_sizes, int n_in,
                              void* d_out, int out_size, void* d_ws, size_t ws_size,
                              hipStream_t stream) {
    const float* Q = (const float*)d_in[0];
    const float* K = (const float*)d_in[1];
    const float* V = (const float*)d_in[2];
    float* out = (float*)d_out;
    hipLaunchKernelGGL(attn_k, dim3(256), dim3(512), 0, stream, Q, K, V, out);
}